// Round 5
// baseline (345.878 us; speedup 1.0000x reference)
//
#include <hip/hip_runtime.h>
#include <stdint.h>

#define PP 196            // 14*14
#define BP 6272           // 32*196

typedef _Float16 half_t;
typedef half_t half8v __attribute__((ext_vector_type(8)));
typedef half_t half4v __attribute__((ext_vector_type(4)));

// ---------------------------------------------------------------------------
// assign kernels: nearest-centroid 4-bit indices, packed 8 per u32, f64 math
// (reproduces np's argmin except at f64-level ties). Centroids staged in LDS
// (R2-proven; rows 16B-aligned so reads merge to ds_read_b128 broadcasts),
// amortized over 4 positions/thread (the LDS broadcast issue rate was the
// assign bottleneck; s_load variant (R4) regressed on SGPR pressure).
// dist = c2 - 2*dot, fma-accumulated ascending d  (== R2 bitwise).
// idx layout: idxp[cb/8][BP]
// ---------------------------------------------------------------------------

template <typename T>
__global__ __launch_bounds__(256) void assign_1x1(
    const T* __restrict__ in, const float* __restrict__ cents,
    uint32_t* __restrict__ idxp, int nchan) {
  __shared__ double s_cent[8][16][4];   // 32 B rows, 16B-aligned
  __shared__ double s_c2[8][16];
  const int chunk = blockIdx.y;
  const int t = threadIdx.x;
  for (int i = t; i < 512; i += 256)
    ((double*)s_cent)[i] = (double)cents[(size_t)chunk * 512 + i];
  __syncthreads();
  if (t < 128) {
    int cb_l = t >> 4, k = t & 15;
    double s = 0.0;
#pragma unroll
    for (int d = 0; d < 4; d++) { double c = s_cent[cb_l][k][d]; s += c * c; }
    s_c2[cb_l][k] = s;
  }
  __syncthreads();
  int pp[4]; bool val[4]; unsigned bb[4], pr[4];
#pragma unroll
  for (int i = 0; i < 4; i++) {
    pp[i] = blockIdx.x * 1024 + t + 256 * i;
    val[i] = pp[i] < BP;
    unsigned b = (unsigned)pp[i] / 196u;
    bb[i] = b; pr[i] = (unsigned)pp[i] - b * 196u;
  }
  uint32_t word[4] = {0, 0, 0, 0};
#pragma unroll 1
  for (int cb_l = 0; cb_l < 8; cb_l++) {
    double xv[4][4];
#pragma unroll
    for (int i = 0; i < 4; i++) {
      const T* xb = in + ((size_t)bb[i] * nchan + chunk * 32 + cb_l * 4) * PP + pr[i];
#pragma unroll
      for (int d = 0; d < 4; d++) xv[i][d] = val[i] ? (double)xb[(size_t)d * PP] : 0.0;
    }
    double best[4]; int bi[4];
#pragma unroll
    for (int i = 0; i < 4; i++) { best[i] = 1e300; bi[i] = 0; }
#pragma unroll
    for (int k = 0; k < 16; k++) {
      double c0 = s_cent[cb_l][k][0], c1 = s_cent[cb_l][k][1];
      double c2v = s_cent[cb_l][k][2], c3 = s_cent[cb_l][k][3];
      double cc2 = s_c2[cb_l][k];
#pragma unroll
      for (int i = 0; i < 4; i++) {
        double dot = 0.0;
        dot = fma(xv[i][0], c0, dot);
        dot = fma(xv[i][1], c1, dot);
        dot = fma(xv[i][2], c2v, dot);
        dot = fma(xv[i][3], c3, dot);
        double dist = cc2 - 2.0 * dot;
        if (dist < best[i]) { best[i] = dist; bi[i] = k; }  // strict <: first-min
      }
    }
#pragma unroll
    for (int i = 0; i < 4; i++) word[i] |= (uint32_t)bi[i] << (4 * cb_l);
  }
#pragma unroll
  for (int i = 0; i < 4; i++)
    if (val[i]) idxp[(size_t)chunk * BP + pp[i]] = word[i];
}

__global__ __launch_bounds__(256) void assign_3x3(
    const double* __restrict__ in, const float* __restrict__ cents,
    uint32_t* __restrict__ idxp) {
  __shared__ double s_cent[8][16][10];  // 9 used + 1 pad -> 80 B rows, 16B-aligned
  __shared__ double s_c2[8][16];
  const int chunk = blockIdx.y;
  const int c0 = chunk * 8;
  const int t = threadIdx.x;
  for (int i = t; i < 1152; i += 256) {
    int cb = i / 144, r = i - cb * 144;
    int k = r / 9, d = r - k * 9;
    s_cent[cb][k][d] = (double)cents[(size_t)(c0 + cb) * 144 + k * 9 + d];
  }
  __syncthreads();
  if (t < 128) {
    int cb_l = t >> 4, k = t & 15;
    double s = 0.0;
#pragma unroll
    for (int d = 0; d < 9; d++) { double c = s_cent[cb_l][k][d]; s += c * c; }
    s_c2[cb_l][k] = s;
  }
  __syncthreads();
  int pp[4]; bool val[4]; unsigned bb[4]; int oh[4], ow[4];
#pragma unroll
  for (int i = 0; i < 4; i++) {
    pp[i] = blockIdx.x * 1024 + t + 256 * i;
    val[i] = pp[i] < BP;
    unsigned b = (unsigned)pp[i] / 196u;
    bb[i] = b;
    int prr = pp[i] - (int)b * 196;
    oh[i] = prr / 14; ow[i] = prr - oh[i] * 14;
  }
  uint32_t word[4] = {0, 0, 0, 0};
#pragma unroll 1
  for (int cb_l = 0; cb_l < 8; cb_l++) {
    double v[4][9];
#pragma unroll
    for (int i = 0; i < 4; i++) {
      const double* base = in + ((size_t)bb[i] * 256 + (c0 + cb_l)) * PP;
#pragma unroll
      for (int r = 0; r < 3; r++) {
#pragma unroll
        for (int cc = 0; cc < 3; cc++) {
          int hh = oh[i] + r - 1, ww = ow[i] + cc - 1;
          bool ok = val[i] & (hh >= 0) & (hh < 14) & (ww >= 0) & (ww < 14);
          v[i][r * 3 + cc] = ok ? base[hh * 14 + ww] : 0.0;
        }
      }
    }
    double best[4]; int bi[4];
#pragma unroll
    for (int i = 0; i < 4; i++) { best[i] = 1e300; bi[i] = 0; }
#pragma unroll
    for (int k = 0; k < 16; k++) {
      double c[9];
#pragma unroll
      for (int d = 0; d < 9; d++) c[d] = s_cent[cb_l][k][d];
      double cc2 = s_c2[cb_l][k];
#pragma unroll
      for (int i = 0; i < 4; i++) {
        double dot = 0.0;
#pragma unroll
        for (int d = 0; d < 9; d++) dot = fma(v[i][d], c[d], dot);
        double dist = cc2 - 2.0 * dot;
        if (dist < best[i]) { best[i] = dist; bi[i] = k; }
      }
    }
#pragma unroll
    for (int i = 0; i < 4; i++) word[i] |= (uint32_t)bi[i] << (4 * cb_l);
  }
#pragma unroll
  for (int i = 0; i < 4; i++)
    if (val[i]) idxp[(size_t)chunk * BP + pp[i]] = word[i];
}

// ---------------------------------------------------------------------------
// accum (f64): out[b][o][p] = act( scale[o]*sum_cb lut[cb][idx][o] + bias[o] (+res) )
// ONE barrier per chunk: double-buffered LDS (2 x 20 KB), ds_write staging of
// chunk ch+1 overlapped with gathers of chunk ch; global prefetch 1 chunk ahead.
// Row layout: per (cb,k) 80 B (16 ch + 16 B pad). Gather bank-quad =
// (5*idx + q) mod 8: bijective in idx mod 8 (5 coprime 8) -> 2-way max = free;
// same-idx lanes broadcast. Staging (4q'+20k mod 32 banks) is 2-way = free.
// grid (49, NOUT/16), block 512: 128 positions x 16 out channels.
// ---------------------------------------------------------------------------
template <int NCB, int NOUT, bool RELU, bool RES, typename OutT>
__global__ __launch_bounds__(512) void accum_f64(
    const float* __restrict__ lut, const uint32_t* __restrict__ idxp,
    const float* __restrict__ scale, const float* __restrict__ bias,
    const float* __restrict__ res, OutT* __restrict__ out) {
  __shared__ float s_lut[2][5120];   // 2 x 20 KB
  const int t = threadIdx.x;
  const int lane = t & 63;
  const int wave = t >> 6;
  const int q = wave & 3;            // output quad (4 channels)
  const int pg = wave >> 2;          // 0..1
  const int p = blockIdx.x * 128 + pg * 64 + lane;
  const int o_base = blockIdx.y * 16;
  // staging slots s0=t, s1=t+512 of 1024: (cb=s>>6, k=(s>>2)&15, q'=s&3)
  const int s0 = t, s1 = t + 512;
  const int cA = s0 >> 6, kA = (s0 >> 2) & 15, qA = s0 & 3;
  const int cB = s1 >> 6, kB = (s1 >> 2) & 15, qB = s1 & 3;
  const float* srcA = lut + ((size_t)cA * 16 + kA) * NOUT + o_base + qA * 4;
  const float* srcB = lut + ((size_t)cB * 16 + kB) * NOUT + o_base + qB * 4;
  const int dA = cA * 320 + kA * 20 + qA * 4;   // float offsets in chunk buffer
  const int dB = cB * 320 + kB * 20 + qB * 4;
  const size_t cs = (size_t)256 * NOUT;         // 16 cb x 16 k per chunk
  constexpr int NCHUNK = NCB / 16;

  // prologue: stage chunk 0 into buf 0; prefetch chunk-1 regs
  float4 va = *(const float4*)srcA;
  float4 vb = *(const float4*)srcB;
  uint32_t w0 = idxp[p];
  uint32_t w1 = idxp[(size_t)BP + p];
  *(float4*)(s_lut[0] + dA) = va;
  *(float4*)(s_lut[0] + dB) = vb;
  if (NCHUNK > 1) {
    va = *(const float4*)(srcA + cs);
    vb = *(const float4*)(srcB + cs);
  }
  __syncthreads();

  double a0 = 0, a1 = 0, a2 = 0, a3 = 0;
  for (int ch = 0; ch < NCHUNK; ch++) {
    // stage chunk ch+1 into the other buffer (no reader touches it yet)
    if (ch + 1 < NCHUNK) {
      float* d = s_lut[(ch + 1) & 1];
      *(float4*)(d + dA) = va;
      *(float4*)(d + dB) = vb;
    }
    if (ch + 2 < NCHUNK) {
      va = *(const float4*)(srcA + (size_t)(ch + 2) * cs);
      vb = *(const float4*)(srcB + (size_t)(ch + 2) * cs);
    }
    uint32_t nw0 = 0, nw1 = 0;
    if (ch + 1 < NCHUNK) {
      nw0 = idxp[(size_t)(2 * ch + 2) * BP + p];
      nw1 = idxp[(size_t)(2 * ch + 3) * BP + p];
    }
    const float* base = s_lut[ch & 1];
#pragma unroll
    for (int cb_l = 0; cb_l < 16; cb_l++) {
      uint32_t w = (cb_l < 8) ? w0 : w1;
      int idx = (int)((w >> (4 * (cb_l & 7))) & 15u);
      const float4 v = *(const float4*)(base + cb_l * 320 + idx * 20 + q * 4);
      a0 += (double)v.x; a1 += (double)v.y; a2 += (double)v.z; a3 += (double)v.w;
    }
    __syncthreads();   // gathers of ch + staging of ch+1 both complete
    w0 = nw0; w1 = nw1;
  }
  const unsigned b = (unsigned)p / 196u;
  const unsigned pr = (unsigned)p - b * 196u;
  const int o = o_base + q * 4;
  const float4 sc = *(const float4*)(scale + o);
  const float4 bs = *(const float4*)(bias + o);
  double r0 = a0 * (double)sc.x + (double)bs.x;
  double r1 = a1 * (double)sc.y + (double)bs.y;
  double r2 = a2 * (double)sc.z + (double)bs.z;
  double r3 = a3 * (double)sc.w + (double)bs.w;
  if (RES) {
    const float* rp = res + ((size_t)b * NOUT + o) * PP + pr;
    r0 += (double)rp[0 * PP]; r1 += (double)rp[1 * PP];
    r2 += (double)rp[2 * PP]; r3 += (double)rp[3 * PP];
  }
  if (RELU) {
    r0 = fmax(r0, 0.0); r1 = fmax(r1, 0.0);
    r2 = fmax(r2, 0.0); r3 = fmax(r3, 0.0);
  }
  OutT* op = out + ((size_t)b * NOUT + o) * PP + pr;
  op[0 * PP] = (OutT)r0; op[1 * PP] = (OutT)r1;
  op[2 * PP] = (OutT)r2; op[3 * PP] = (OutT)r3;
}

// ---------------------------------------------------------------------------
// accum3 (f16 LUT, f32 accumulate): final layer only (no downstream argmin).
// One b128 gather = 8 channels. Same one-barrier dbuf structure; rows 48 B
// (16 f16 ch + 16 B pad): gather bank-quad = (3*idx + h) mod 8, bijective in
// idx mod 8 -> 2-way = free. 2 x 12 KB LDS. grid (49, 64), block 256.
// ---------------------------------------------------------------------------
__global__ __launch_bounds__(256) void accum3_f16(
    const half_t* __restrict__ lut16, const uint32_t* __restrict__ idxp,
    const float* __restrict__ scale, const float* __restrict__ bias,
    const float* __restrict__ res, float* __restrict__ out) {
  __shared__ half_t s16[2][6144];    // 2 x 12 KB
  const int t = threadIdx.x;
  const int lane = t & 63;
  const int wave = t >> 6;           // 0..3
  const int h = wave & 1;            // channel half (8 f16 ch)
  const int pg = wave >> 1;          // 0..1
  const int p = blockIdx.x * 128 + pg * 64 + lane;
  const int o_base = blockIdx.y * 16;
  // staging slots s0=t, s1=t+256 of 512: (cb=s>>5, k=(s>>1)&15, hh=s&1)
  const int s0 = t, s1 = t + 256;
  const int cA = s0 >> 5, kA = (s0 >> 1) & 15, hA = s0 & 1;
  const int cB = s1 >> 5, kB = (s1 >> 1) & 15, hB = s1 & 1;
  const half_t* srcA = lut16 + ((size_t)cA * 16 + kA) * 1024 + o_base + hA * 8;
  const half_t* srcB = lut16 + ((size_t)cB * 16 + kB) * 1024 + o_base + hB * 8;
  const int dA = cA * 384 + kA * 24 + hA * 8;   // half offsets in chunk buffer
  const int dB = cB * 384 + kB * 24 + hB * 8;
  const size_t cs = (size_t)16 * 16 * 1024;     // 16 cb per chunk
  constexpr int NCHUNK = 4;

  half8v va = *(const half8v*)srcA;
  half8v vb = *(const half8v*)srcB;
  uint32_t w0 = idxp[p];
  uint32_t w1 = idxp[(size_t)BP + p];
  *(half8v*)(s16[0] + dA) = va;
  *(half8v*)(s16[0] + dB) = vb;
  va = *(const half8v*)(srcA + cs);
  vb = *(const half8v*)(srcB + cs);
  __syncthreads();

  float a[8];
#pragma unroll
  for (int i = 0; i < 8; i++) a[i] = 0.f;
  for (int ch = 0; ch < NCHUNK; ch++) {
    if (ch + 1 < NCHUNK) {
      half_t* d = s16[(ch + 1) & 1];
      *(half8v*)(d + dA) = va;
      *(half8v*)(d + dB) = vb;
    }
    if (ch + 2 < NCHUNK) {
      va = *(const half8v*)(srcA + (size_t)(ch + 2) * cs);
      vb = *(const half8v*)(srcB + (size_t)(ch + 2) * cs);
    }
    uint32_t nw0 = 0, nw1 = 0;
    if (ch + 1 < NCHUNK) {
      nw0 = idxp[(size_t)(2 * ch + 2) * BP + p];
      nw1 = idxp[(size_t)(2 * ch + 3) * BP + p];
    }
    const half_t* base = s16[ch & 1];
#pragma unroll
    for (int cb_l = 0; cb_l < 16; cb_l++) {
      uint32_t w = (cb_l < 8) ? w0 : w1;
      int idx = (int)((w >> (4 * (cb_l & 7))) & 15u);
      const half8v v = *(const half8v*)(base + cb_l * 384 + idx * 24 + h * 8);
#pragma unroll
      for (int i = 0; i < 8; i++) a[i] += (float)v[i];
    }
    __syncthreads();
    w0 = nw0; w1 = nw1;
  }
  const unsigned b = (unsigned)p / 196u;
  const unsigned pr = (unsigned)p - b * 196u;
  const int o = o_base + h * 8;
  const float* rp = res + ((size_t)b * 1024 + o) * PP + pr;
  float* op = out + ((size_t)b * 1024 + o) * PP + pr;
#pragma unroll
  for (int i = 0; i < 8; i++) {
    float v = a[i] * scale[o + i] + bias[o + i] + rp[(size_t)i * PP];
    op[(size_t)i * PP] = fmaxf(v, 0.f);
  }
}

// f32 -> f16 LUT conversion (1,048,576 elements)
__global__ __launch_bounds__(256) void cvt_f16(
    const float* __restrict__ src, half_t* __restrict__ dst, int n) {
  int i = (blockIdx.x * 256 + threadIdx.x) * 4;
  if (i < n) {
    float4 v = *(const float4*)(src + i);
    half4v o;
    o[0] = (half_t)v.x; o[1] = (half_t)v.y; o[2] = (half_t)v.z; o[3] = (half_t)v.w;
    *(half4v*)(dst + i) = o;
  }
}

// ---------------------------------------------------------------------------

extern "C" void kernel_launch(void* const* d_in, const int* in_sizes, int n_in,
                              void* d_out, int out_size, void* d_ws, size_t ws_size,
                              hipStream_t stream) {
  const float* x   = (const float*)d_in[0];   // [32,1024,14,14]
  const float* c1c = (const float*)d_in[1];
  const float* c1l = (const float*)d_in[2];
  const float* c1s = (const float*)d_in[3];
  const float* c1b = (const float*)d_in[4];
  const float* c2c = (const float*)d_in[5];
  const float* c2l = (const float*)d_in[6];
  const float* c2s = (const float*)d_in[7];
  const float* c2b = (const float*)d_in[8];
  const float* c3c = (const float*)d_in[9];
  const float* c3l = (const float*)d_in[10];  // [64,16,1024]
  const float* c3s = (const float*)d_in[11];
  const float* c3b = (const float*)d_in[12];

  const size_t sz_i1 = (size_t)32 * BP * 4;
  const size_t sz_i2 = (size_t)32 * BP * 4;
  const size_t sz_i3 = (size_t)8 * BP * 4;
  const size_t sz_l16 = (size_t)64 * 16 * 1024 * 2;   // 2 MB
  const size_t sz_o64 = (size_t)BP * 256 * 8;          // 12.85 MB

  char* w = (char*)d_ws;
  uint32_t* i1 = (uint32_t*)w; w += sz_i1;
  uint32_t* i2 = (uint32_t*)w; w += sz_i2;
  uint32_t* i3 = (uint32_t*)w; w += sz_i3;
  const size_t base_need = sz_i1 + sz_i2 + sz_i3;
  bool use_f16 = (ws_size >= base_need + sz_l16);
  half_t* l16 = (half_t*)w;
  if (use_f16) w += sz_l16;
  double *out1, *out2;
  if (ws_size >= (size_t)(w - (char*)d_ws) + 2 * sz_o64) {
    out1 = (double*)w;
    out2 = (double*)(w + sz_o64);
  } else {
    // d_out (25.69 MB f32) == exactly two 12.85 MB f64 arrays; the final
    // accum3 reads only i3/x/lut, then overwrites all of d_out.
    out1 = (double*)d_out;
    out2 = out1 + (size_t)BP * 256;
  }

  const dim3 blkA(256);
  if (use_f16)
    cvt_f16<<<dim3(1024), blkA, 0, stream>>>(c3l, l16, 64 * 16 * 1024);
  // layer 1: 1x1, 256 codebooks (dsub=4) over 1024 input channels
  assign_1x1<float><<<dim3(7, 32), blkA, 0, stream>>>(x, c1c, i1, 1024);
  accum_f64<256, 256, true, false, double><<<dim3(49, 16), dim3(512), 0, stream>>>(
      c1l, i1, c1s, c1b, nullptr, out1);
  // layer 2: 3x3, 256 codebooks (dsub=9)
  assign_3x3<<<dim3(7, 32), blkA, 0, stream>>>(out1, c2c, i2);
  accum_f64<256, 256, true, false, double><<<dim3(49, 16), dim3(512), 0, stream>>>(
      c2l, i2, c2s, c2b, nullptr, out2);
  // layer 3: 1x1, 64 codebooks over 256 channels; fused residual + relu
  assign_1x1<double><<<dim3(7, 8), blkA, 0, stream>>>(out2, c3c, i3, 256);
  if (use_f16)
    accum3_f16<<<dim3(49, 64), blkA, 0, stream>>>(
        l16, i3, c3s, c3b, x, (float*)d_out);
  else
    accum_f64<64, 1024, true, true, float><<<dim3(49, 64), dim3(512), 0, stream>>>(
        c3l, i3, c3s, c3b, x, (float*)d_out);
}

// Round 6
// 291.530 us; speedup vs baseline: 1.1864x; 1.1864x over previous
//
#include <hip/hip_runtime.h>
#include <stdint.h>

#define PP 196            // 14*14
#define BP 6272           // 32*196

typedef _Float16 half_t;
typedef half_t half8v __attribute__((ext_vector_type(8)));
typedef half_t half4v __attribute__((ext_vector_type(4)));

// ---------------------------------------------------------------------------
// assign kernels: nearest-centroid 4-bit indices, packed 8 per u32, f64 math
// (reproduces np's argmin except at f64-level ties; R2-proven formulation:
// dot = fma ascending d, dist = c2 - 2*dot, strict < first-min).
// Centroids in LDS as f64 rows [c2, c0..c_{d-1}] (16B-aligned) -> per-k reads
// merge to ds_read_b128 broadcasts (2x fewer LDS instr than R2's b64 path).
// POS positions/thread amortizes the broadcasts; grid sized to keep >=6 waves/CU
// (R5's 4-pos variant collapsed to 3.5 waves/CU -> 70us latency-bound).
// idx layout: idxp[cb/8][BP]
// ---------------------------------------------------------------------------

template <typename T, int POS>
__global__ __launch_bounds__(256) void assign_1x1(
    const T* __restrict__ in, const float* __restrict__ cents,
    uint32_t* __restrict__ idxp, int nchan) {
  __shared__ double s_cent[8][16][6];   // [c2, c0..c3, pad]: 48 B rows
  const int chunk = blockIdx.y;
  const int t = threadIdx.x;
  for (int i = t; i < 512; i += 256) {
    int cb = i >> 6, r = i & 63;        // r = k*4 + d
    s_cent[cb][r >> 2][1 + (r & 3)] = (double)cents[(size_t)chunk * 512 + i];
  }
  __syncthreads();
  if (t < 128) {
    int cb = t >> 4, k = t & 15;
    double s = 0.0;
#pragma unroll
    for (int d = 0; d < 4; d++) { double c = s_cent[cb][k][1 + d]; s += c * c; }
    s_cent[cb][k][0] = s;
  }
  __syncthreads();
  int pp[POS]; bool val[POS]; unsigned bb[POS], pr[POS];
#pragma unroll
  for (int i = 0; i < POS; i++) {
    pp[i] = blockIdx.x * (256 * POS) + t + 256 * i;
    val[i] = pp[i] < BP;
    unsigned b = (unsigned)pp[i] / 196u;
    bb[i] = b; pr[i] = (unsigned)pp[i] - b * 196u;
  }
  uint32_t word[POS];
#pragma unroll
  for (int i = 0; i < POS; i++) word[i] = 0;
#pragma unroll 1
  for (int cb = 0; cb < 8; cb++) {
    double xv[POS][4];
#pragma unroll
    for (int i = 0; i < POS; i++) {
      const T* xb = in + ((size_t)bb[i] * nchan + chunk * 32 + cb * 4) * PP + pr[i];
#pragma unroll
      for (int d = 0; d < 4; d++) xv[i][d] = val[i] ? (double)xb[(size_t)d * PP] : 0.0;
    }
    double best[POS]; int bi[POS];
#pragma unroll
    for (int i = 0; i < POS; i++) { best[i] = 1e300; bi[i] = 0; }
#pragma unroll
    for (int k = 0; k < 16; k++) {
      double2 cA = *(const double2*)&s_cent[cb][k][0];  // (c2, c0)
      double2 cB = *(const double2*)&s_cent[cb][k][2];  // (c1, c2)
      double c3 = s_cent[cb][k][4];
#pragma unroll
      for (int i = 0; i < POS; i++) {
        double dot = 0.0;
        dot = fma(xv[i][0], cA.y, dot);
        dot = fma(xv[i][1], cB.x, dot);
        dot = fma(xv[i][2], cB.y, dot);
        dot = fma(xv[i][3], c3, dot);
        double dist = cA.x - 2.0 * dot;
        if (dist < best[i]) { best[i] = dist; bi[i] = k; }
      }
    }
#pragma unroll
    for (int i = 0; i < POS; i++) word[i] |= (uint32_t)bi[i] << (4 * cb);
  }
#pragma unroll
  for (int i = 0; i < POS; i++)
    if (val[i]) idxp[(size_t)chunk * BP + pp[i]] = word[i];
}

__global__ __launch_bounds__(256) void assign_3x3(
    const double* __restrict__ in, const float* __restrict__ cents,
    uint32_t* __restrict__ idxp) {
  __shared__ double s_cent[8][16][10];  // [c2, c0..c8]: 80 B rows, 16B-aligned
  const int chunk = blockIdx.y;
  const int c0g = chunk * 8;
  const int t = threadIdx.x;
  for (int i = t; i < 1152; i += 256) {
    int cb = i / 144, r = i - cb * 144;
    int k = r / 9, d = r - k * 9;
    s_cent[cb][k][1 + d] = (double)cents[(size_t)(c0g + cb) * 144 + k * 9 + d];
  }
  __syncthreads();
  if (t < 128) {
    int cb = t >> 4, k = t & 15;
    double s = 0.0;
#pragma unroll
    for (int d = 0; d < 9; d++) { double c = s_cent[cb][k][1 + d]; s += c * c; }
    s_cent[cb][k][0] = s;
  }
  __syncthreads();
  constexpr int POS = 2;
  int pp[POS]; bool val[POS]; unsigned bb[POS]; int oh[POS], ow[POS];
#pragma unroll
  for (int i = 0; i < POS; i++) {
    pp[i] = blockIdx.x * (256 * POS) + t + 256 * i;
    val[i] = pp[i] < BP;
    unsigned b = (unsigned)pp[i] / 196u;
    bb[i] = b;
    int prr = pp[i] - (int)b * 196;
    oh[i] = prr / 14; ow[i] = prr - oh[i] * 14;
  }
  uint32_t word[POS];
#pragma unroll
  for (int i = 0; i < POS; i++) word[i] = 0;
#pragma unroll 1
  for (int cb = 0; cb < 8; cb++) {
    double v[POS][9];
#pragma unroll
    for (int i = 0; i < POS; i++) {
      const double* base = in + ((size_t)bb[i] * 256 + (c0g + cb)) * PP;
#pragma unroll
      for (int r = 0; r < 3; r++) {
#pragma unroll
        for (int cc = 0; cc < 3; cc++) {
          int hh = oh[i] + r - 1, ww = ow[i] + cc - 1;
          bool ok = val[i] & (hh >= 0) & (hh < 14) & (ww >= 0) & (ww < 14);
          v[i][r * 3 + cc] = ok ? base[hh * 14 + ww] : 0.0;
        }
      }
    }
    double best[POS]; int bi[POS];
#pragma unroll
    for (int i = 0; i < POS; i++) { best[i] = 1e300; bi[i] = 0; }
#pragma unroll
    for (int k = 0; k < 16; k++) {
      double2 cA = *(const double2*)&s_cent[cb][k][0];  // (c2, c0)
      double2 cB = *(const double2*)&s_cent[cb][k][2];  // (c1, c2)
      double2 cC = *(const double2*)&s_cent[cb][k][4];  // (c3, c4)
      double2 cD = *(const double2*)&s_cent[cb][k][6];  // (c5, c6)
      double2 cE = *(const double2*)&s_cent[cb][k][8];  // (c7, c8)
#pragma unroll
      for (int i = 0; i < POS; i++) {
        double dot = 0.0;
        dot = fma(v[i][0], cA.y, dot);
        dot = fma(v[i][1], cB.x, dot);
        dot = fma(v[i][2], cB.y, dot);
        dot = fma(v[i][3], cC.x, dot);
        dot = fma(v[i][4], cC.y, dot);
        dot = fma(v[i][5], cD.x, dot);
        dot = fma(v[i][6], cD.y, dot);
        dot = fma(v[i][7], cE.x, dot);
        dot = fma(v[i][8], cE.y, dot);
        double dist = cA.x - 2.0 * dot;
        if (dist < best[i]) { best[i] = dist; bi[i] = k; }
      }
    }
#pragma unroll
    for (int i = 0; i < POS; i++) word[i] |= (uint32_t)bi[i] << (4 * cb);
  }
#pragma unroll
  for (int i = 0; i < POS; i++)
    if (val[i]) idxp[(size_t)chunk * BP + pp[i]] = word[i];
}

// ---------------------------------------------------------------------------
// accum (f64) — EXACT R2 structure (measured 53.4 us, conflicts 1.6e6 = free):
// two barriers/chunk, loads inside the barrier pair, 36-float k-stride pad.
// grid (49, NOUT/16), block 512: 128 positions x 16 out channels.
// ---------------------------------------------------------------------------
template <int NCB, int NOUT, bool RELU, bool RES, typename OutT>
__global__ __launch_bounds__(512) void accum_f64(
    const float* __restrict__ lut, const uint32_t* __restrict__ idxp,
    const float* __restrict__ scale, const float* __restrict__ bias,
    const float* __restrict__ res, OutT* __restrict__ out) {
  __shared__ float s_lut[16 * 16 * 36];  // 36 KB
  const int t = threadIdx.x;
  const int lane = t & 63;
  const int wave = t >> 6;
  const int q = wave & 3;          // output quad (4 channels)
  const int pg = wave >> 2;        // 0..1
  const int p = blockIdx.x * 128 + pg * 64 + lane;
  const int o_base = blockIdx.y * 16;
  const int r = t >> 1, h = t & 1;          // staging: row r=(cb,k), half h
  const int cb_ls = r >> 4, ks = r & 15;
  double a0 = 0, a1 = 0, a2 = 0, a3 = 0;
  constexpr int NCHUNK = NCB / 16;
  for (int ch = 0; ch < NCHUNK; ch++) {
    __syncthreads();               // prior chunk's gathers done before overwrite
    uint32_t w0 = idxp[(size_t)(ch * 2) * BP + p];
    uint32_t w1 = idxp[(size_t)(ch * 2 + 1) * BP + p];
    {
      const float* g = lut + (((size_t)(ch * 16 + cb_ls)) * 16 + ks) * NOUT + o_base + h * 8;
      float4 va = *(const float4*)g;
      float4 vb = *(const float4*)(g + 4);
      float* sd = s_lut + cb_ls * 576 + ks * 36 + h * 8;
      *(float4*)sd = va;
      *(float4*)(sd + 4) = vb;
    }
    __syncthreads();               // chunk published
#pragma unroll
    for (int cb_l = 0; cb_l < 16; cb_l++) {
      uint32_t w = (cb_l < 8) ? w0 : w1;
      int idx = (int)((w >> (4 * (cb_l & 7))) & 15u);
      const float4 v = *(const float4*)(s_lut + cb_l * 576 + idx * 36 + q * 4);
      a0 += (double)v.x; a1 += (double)v.y; a2 += (double)v.z; a3 += (double)v.w;
    }
  }
  const unsigned b = (unsigned)p / 196u;
  const unsigned pr = (unsigned)p - b * 196u;
  const int o = o_base + q * 4;
  const float4 sc = *(const float4*)(scale + o);
  const float4 bs = *(const float4*)(bias + o);
  double r0 = a0 * (double)sc.x + (double)bs.x;
  double r1 = a1 * (double)sc.y + (double)bs.y;
  double r2 = a2 * (double)sc.z + (double)bs.z;
  double r3 = a3 * (double)sc.w + (double)bs.w;
  if (RES) {
    const float* rp = res + ((size_t)b * NOUT + o) * PP + pr;
    r0 += (double)rp[0 * PP]; r1 += (double)rp[1 * PP];
    r2 += (double)rp[2 * PP]; r3 += (double)rp[3 * PP];
  }
  if (RELU) {
    r0 = fmax(r0, 0.0); r1 = fmax(r1, 0.0);
    r2 = fmax(r2, 0.0); r3 = fmax(r3, 0.0);
  }
  OutT* op = out + ((size_t)b * NOUT + o) * PP + pr;
  op[0 * PP] = (OutT)r0; op[1 * PP] = (OutT)r1;
  op[2 * PP] = (OutT)r2; op[3 * PP] = (OutT)r3;
}

// ---------------------------------------------------------------------------
// accum3 (f16 LUT, f32 accumulate): final layer only (no downstream argmin).
// R2-style two-barrier staging. Rows 40 halfs (80 B): gather bank-quad =
// (5*idx + h) mod 8, bijective in idx mod 8 -> 2-way max = free. 20 KB LDS.
// grid (49, 64), block 256 (4 waves): 128 positions x 16 channels.
// ---------------------------------------------------------------------------
__global__ __launch_bounds__(256) void accum3_f16(
    const half_t* __restrict__ lut16, const uint32_t* __restrict__ idxp,
    const float* __restrict__ scale, const float* __restrict__ bias,
    const float* __restrict__ res, float* __restrict__ out) {
  __shared__ half_t s16[16 * 640];   // 20 KB
  const int t = threadIdx.x;
  const int lane = t & 63;
  const int wave = t >> 6;           // 0..3
  const int h = wave & 1;            // channel half (8 f16 ch)
  const int pg = wave >> 1;          // 0..1
  const int p = blockIdx.x * 128 + pg * 64 + lane;
  const int o_base = blockIdx.y * 16;
  // staging slots s0=t, s1=t+256 of 512: (cb=s>>5, k=(s>>1)&15, hh=s&1)
  const int s0 = t, s1 = t + 256;
  const int cA = s0 >> 5, kA = (s0 >> 1) & 15, hA = s0 & 1;
  const int cB = s1 >> 5, kB = (s1 >> 1) & 15, hB = s1 & 1;
  const size_t cs = (size_t)16 * 16 * 1024;     // 16 cb per chunk
  constexpr int NCHUNK = 4;
  float a[8];
#pragma unroll
  for (int i = 0; i < 8; i++) a[i] = 0.f;
  for (int ch = 0; ch < NCHUNK; ch++) {
    __syncthreads();
    uint32_t w0 = idxp[(size_t)(ch * 2) * BP + p];
    uint32_t w1 = idxp[(size_t)(ch * 2 + 1) * BP + p];
    {
      const half_t* gA = lut16 + (size_t)ch * cs + ((size_t)cA * 16 + kA) * 1024 + o_base + hA * 8;
      const half_t* gB = lut16 + (size_t)ch * cs + ((size_t)cB * 16 + kB) * 1024 + o_base + hB * 8;
      half8v va = *(const half8v*)gA;
      half8v vb = *(const half8v*)gB;
      *(half8v*)(s16 + cA * 640 + kA * 40 + hA * 8) = va;
      *(half8v*)(s16 + cB * 640 + kB * 40 + hB * 8) = vb;
    }
    __syncthreads();
#pragma unroll
    for (int cb_l = 0; cb_l < 16; cb_l++) {
      uint32_t w = (cb_l < 8) ? w0 : w1;
      int idx = (int)((w >> (4 * (cb_l & 7))) & 15u);
      const half8v v = *(const half8v*)(s16 + cb_l * 640 + idx * 40 + h * 8);
#pragma unroll
      for (int i = 0; i < 8; i++) a[i] += (float)v[i];
    }
  }
  const unsigned b = (unsigned)p / 196u;
  const unsigned pr = (unsigned)p - b * 196u;
  const int o = o_base + h * 8;
  const float* rp = res + ((size_t)b * 1024 + o) * PP + pr;
  float* op = out + ((size_t)b * 1024 + o) * PP + pr;
#pragma unroll
  for (int i = 0; i < 8; i++) {
    float v = a[i] * scale[o + i] + bias[o + i] + rp[(size_t)i * PP];
    op[(size_t)i * PP] = fmaxf(v, 0.f);
  }
}

// f32 -> f16 LUT conversion (1,048,576 elements)
__global__ __launch_bounds__(256) void cvt_f16(
    const float* __restrict__ src, half_t* __restrict__ dst, int n) {
  int i = (blockIdx.x * 256 + threadIdx.x) * 4;
  if (i < n) {
    float4 v = *(const float4*)(src + i);
    half4v o;
    o[0] = (half_t)v.x; o[1] = (half_t)v.y; o[2] = (half_t)v.z; o[3] = (half_t)v.w;
    *(half4v*)(dst + i) = o;
  }
}

// ---------------------------------------------------------------------------

extern "C" void kernel_launch(void* const* d_in, const int* in_sizes, int n_in,
                              void* d_out, int out_size, void* d_ws, size_t ws_size,
                              hipStream_t stream) {
  const float* x   = (const float*)d_in[0];   // [32,1024,14,14]
  const float* c1c = (const float*)d_in[1];
  const float* c1l = (const float*)d_in[2];
  const float* c1s = (const float*)d_in[3];
  const float* c1b = (const float*)d_in[4];
  const float* c2c = (const float*)d_in[5];
  const float* c2l = (const float*)d_in[6];
  const float* c2s = (const float*)d_in[7];
  const float* c2b = (const float*)d_in[8];
  const float* c3c = (const float*)d_in[9];
  const float* c3l = (const float*)d_in[10];  // [64,16,1024]
  const float* c3s = (const float*)d_in[11];
  const float* c3b = (const float*)d_in[12];

  const size_t sz_i1 = (size_t)32 * BP * 4;
  const size_t sz_i2 = (size_t)32 * BP * 4;
  const size_t sz_i3 = (size_t)8 * BP * 4;
  const size_t sz_l16 = (size_t)64 * 16 * 1024 * 2;   // 2 MB
  const size_t sz_o64 = (size_t)BP * 256 * 8;          // 12.85 MB

  char* w = (char*)d_ws;
  uint32_t* i1 = (uint32_t*)w; w += sz_i1;
  uint32_t* i2 = (uint32_t*)w; w += sz_i2;
  uint32_t* i3 = (uint32_t*)w; w += sz_i3;
  const size_t base_need = sz_i1 + sz_i2 + sz_i3;
  bool use_f16 = (ws_size >= base_need + sz_l16);
  half_t* l16 = (half_t*)w;
  if (use_f16) w += sz_l16;
  double *out1, *out2;
  if (ws_size >= (size_t)(w - (char*)d_ws) + 2 * sz_o64) {
    out1 = (double*)w;
    out2 = (double*)(w + sz_o64);
  } else {
    // d_out (25.69 MB f32) == exactly two 12.85 MB f64 arrays; the final
    // accum3 reads only i3/x/lut, then overwrites all of d_out.
    out1 = (double*)d_out;
    out2 = out1 + (size_t)BP * 256;
  }

  const dim3 blkA(256);
  if (use_f16)
    cvt_f16<<<dim3(1024), blkA, 0, stream>>>(c3l, l16, 64 * 16 * 1024);
  // layer 1: 1x1, 256 codebooks (dsub=4) over 1024 input channels
  assign_1x1<float, 2><<<dim3(13, 32), blkA, 0, stream>>>(x, c1c, i1, 1024);
  accum_f64<256, 256, true, false, double><<<dim3(49, 16), dim3(512), 0, stream>>>(
      c1l, i1, c1s, c1b, nullptr, out1);
  // layer 2: 3x3, 256 codebooks (dsub=9)
  assign_3x3<<<dim3(13, 32), blkA, 0, stream>>>(out1, c2c, i2);
  accum_f64<256, 256, true, false, double><<<dim3(49, 16), dim3(512), 0, stream>>>(
      c2l, i2, c2s, c2b, nullptr, out2);
  // layer 3: 1x1, 64 codebooks over 256 channels; fused residual + relu
  assign_1x1<double, 1><<<dim3(25, 8), blkA, 0, stream>>>(out2, c3c, i3, 256);
  if (use_f16)
    accum3_f16<<<dim3(49, 64), blkA, 0, stream>>>(
        l16, i3, c3s, c3b, x, (float*)d_out);
  else
    accum_f64<64, 1024, true, true, float><<<dim3(49, 64), dim3(512), 0, stream>>>(
        c3l, i3, c3s, c3b, x, (float*)d_out);
}

// Round 7
// 266.373 us; speedup vs baseline: 1.2985x; 1.0944x over previous
//
#include <hip/hip_runtime.h>
#include <stdint.h>

#define PP 196            // 14*14
#define BP 6272           // 32*196

typedef _Float16 half_t;
typedef half_t half8v __attribute__((ext_vector_type(8)));
typedef half_t half2v __attribute__((ext_vector_type(2)));

// ---------------------------------------------------------------------------
// assign kernels: nearest-centroid 4-bit indices, packed 8 per u32.
// f32 SCREEN + f64 FIXUP: screen computes distances in f32 and tracks
// best/second-best; iff any lane's gap < TAU the wave re-runs that codebook
// with the bitwise-R2 f64 formula (exact). f32 error bound ~2e-5 << TAU, so
// the final decision always equals the f64-exact argmin == the proven path.
// idx layout: idxp[cb/8][BP]
// ---------------------------------------------------------------------------

template <typename T>
__global__ __launch_bounds__(256) void assign_1x1(
    const T* __restrict__ in, const float* __restrict__ cents,
    uint32_t* __restrict__ idxp, int nchan) {
  __shared__ float  sf[8][16][4];     // screen rows (16 B, one b128)
  __shared__ double sd[8][16][6];     // [c2, c0..c3, pad]: 48 B rows
  const int chunk = blockIdx.y;
  const int t = threadIdx.x;
  for (int i = t; i < 512; i += 256) {
    float c = cents[(size_t)chunk * 512 + i];
    int cb = i >> 6, r = i & 63;      // r = k*4 + d
    sf[cb][r >> 2][r & 3] = c;
    sd[cb][r >> 2][1 + (r & 3)] = (double)c;
  }
  __syncthreads();
  if (t < 128) {
    int cb = t >> 4, k = t & 15;
    double s = 0.0;
#pragma unroll
    for (int d = 0; d < 4; d++) { double c = sd[cb][k][1 + d]; s += c * c; }
    sd[cb][k][0] = s;
  }
  __syncthreads();
  const int p = blockIdx.x * 256 + t;
  if (p >= BP) return;
  const unsigned b = (unsigned)p / 196u;
  const unsigned pr = (unsigned)p - b * 196u;
  const T* xb = in + ((size_t)b * nchan + chunk * 32) * PP + pr;
  T xr[32];
#pragma unroll
  for (int i = 0; i < 32; i++) xr[i] = xb[(size_t)i * PP];
  float xs2[32];
#pragma unroll
  for (int i = 0; i < 32; i++) xs2[i] = 2.f * (float)xr[i];
  uint32_t word = 0;
#pragma unroll 1
  for (int cb = 0; cb < 8; cb++) {
    float best = 1e30f, sec = 1e30f; int bi = 0;
#pragma unroll
    for (int k = 0; k < 16; k++) {
      const float4 c = *(const float4*)&sf[cb][k][0];
      float dist = c.x * (c.x - xs2[cb * 4 + 0]);
      dist = fmaf(c.y, c.y - xs2[cb * 4 + 1], dist);
      dist = fmaf(c.z, c.z - xs2[cb * 4 + 2], dist);
      dist = fmaf(c.w, c.w - xs2[cb * 4 + 3], dist);
      if (dist < best) { sec = best; best = dist; bi = k; }
      else sec = fminf(sec, dist);
    }
    if (__any(sec - best < 2e-4f)) {
      // exact R2 f64 path (bitwise-identical formulation)
      double xv[4];
#pragma unroll
      for (int d = 0; d < 4; d++) xv[d] = (double)xr[cb * 4 + d];
      double bb = 1e300; int bi64 = 0;
#pragma unroll
      for (int k = 0; k < 16; k++) {
        double dot = 0.0;
#pragma unroll
        for (int d = 0; d < 4; d++) dot = fma(xv[d], sd[cb][k][1 + d], dot);
        double dist = sd[cb][k][0] - 2.0 * dot;
        if (dist < bb) { bb = dist; bi64 = k; }   // strict <: first-min
      }
      bi = bi64;
    }
    word |= (uint32_t)bi << (4 * cb);
  }
  idxp[(size_t)chunk * BP + p] = word;
}

__global__ __launch_bounds__(256) void assign_3x3(
    const double* __restrict__ in, const float* __restrict__ cents,
    uint32_t* __restrict__ idxp) {
  __shared__ float  sf[8][16][12];    // [c2f, c0..c8, pad, pad]: 48 B rows
  __shared__ double sd[8][16][10];    // [c2, c0..c8]: 80 B rows
  const int chunk = blockIdx.y;
  const int c0g = chunk * 8;
  const int t = threadIdx.x;
  for (int i = t; i < 1152; i += 256) {
    int cb = i / 144, r = i - cb * 144;
    int k = r / 9, d = r - k * 9;
    float c = cents[(size_t)(c0g + cb) * 144 + k * 9 + d];
    sf[cb][k][1 + d] = c;
    sd[cb][k][1 + d] = (double)c;
  }
  __syncthreads();
  if (t < 128) {
    int cb = t >> 4, k = t & 15;
    double s = 0.0;
    float s32 = 0.f;
#pragma unroll
    for (int d = 0; d < 9; d++) {
      double c = sd[cb][k][1 + d]; s += c * c;
      float cf = sf[cb][k][1 + d]; s32 += cf * cf;
    }
    sd[cb][k][0] = s;
    sf[cb][k][0] = s32;
  }
  __syncthreads();
  const int p = blockIdx.x * 256 + t;
  if (p >= BP) return;
  const unsigned b = (unsigned)p / 196u;
  const unsigned pr = (unsigned)p - b * 196u;
  const int oh = pr / 14, ow = pr - oh * 14;
  uint32_t word = 0;
#pragma unroll 1
  for (int cb = 0; cb < 8; cb++) {
    const double* base = in + ((size_t)b * 256 + (c0g + cb)) * PP;
    double v64[9]; float v32[9];
#pragma unroll
    for (int r = 0; r < 3; r++) {
#pragma unroll
      for (int cc = 0; cc < 3; cc++) {
        int hh = oh + r - 1, ww = ow + cc - 1;
        bool ok = (hh >= 0) & (hh < 14) & (ww >= 0) & (ww < 14);
        double v = ok ? base[hh * 14 + ww] : 0.0;
        v64[r * 3 + cc] = v;
        v32[r * 3 + cc] = (float)v;
      }
    }
    float best = 1e30f, sec = 1e30f; int bi = 0;
#pragma unroll
    for (int k = 0; k < 16; k++) {
      const float4 cA = *(const float4*)&sf[cb][k][0];  // c2f,c0,c1,c2
      const float4 cB = *(const float4*)&sf[cb][k][4];  // c3..c6
      const float4 cC = *(const float4*)&sf[cb][k][8];  // c7,c8,pad,pad
      float dot = v32[0] * cA.y;
      dot = fmaf(v32[1], cA.z, dot);
      dot = fmaf(v32[2], cA.w, dot);
      dot = fmaf(v32[3], cB.x, dot);
      dot = fmaf(v32[4], cB.y, dot);
      dot = fmaf(v32[5], cB.z, dot);
      dot = fmaf(v32[6], cB.w, dot);
      dot = fmaf(v32[7], cC.x, dot);
      dot = fmaf(v32[8], cC.y, dot);
      float dist = fmaf(-2.f, dot, cA.x);
      if (dist < best) { sec = best; best = dist; bi = k; }
      else sec = fminf(sec, dist);
    }
    if (__any(sec - best < 4e-4f)) {
      double bb = 1e300; int bi64 = 0;
#pragma unroll
      for (int k = 0; k < 16; k++) {
        double dot = 0.0;
#pragma unroll
        for (int d = 0; d < 9; d++) dot = fma(v64[d], sd[cb][k][1 + d], dot);
        double dist = sd[cb][k][0] - 2.0 * dot;
        if (dist < bb) { bb = dist; bi64 = k; }
      }
      bi = bi64;
    }
    word |= (uint32_t)bi << (4 * cb);
  }
  idxp[(size_t)chunk * BP + p] = word;
}

// ---------------------------------------------------------------------------
// accum (f64) — EXACT R2 structure (measured 53.4-54.2 us, conflicts = free).
// DO NOT TOUCH: one-barrier dbuf (R5) and register-prefetch (R4) both regressed.
// grid (49, NOUT/16), block 512: 128 positions x 16 out channels.
// ---------------------------------------------------------------------------
template <int NCB, int NOUT, bool RELU, bool RES, typename OutT>
__global__ __launch_bounds__(512) void accum_f64(
    const float* __restrict__ lut, const uint32_t* __restrict__ idxp,
    const float* __restrict__ scale, const float* __restrict__ bias,
    const float* __restrict__ res, OutT* __restrict__ out) {
  __shared__ float s_lut[16 * 16 * 36];  // 36 KB
  const int t = threadIdx.x;
  const int lane = t & 63;
  const int wave = t >> 6;
  const int q = wave & 3;          // output quad (4 channels)
  const int pg = wave >> 2;        // 0..1
  const int p = blockIdx.x * 128 + pg * 64 + lane;
  const int o_base = blockIdx.y * 16;
  const int r = t >> 1, h = t & 1;          // staging: row r=(cb,k), half h
  const int cb_ls = r >> 4, ks = r & 15;
  double a0 = 0, a1 = 0, a2 = 0, a3 = 0;
  constexpr int NCHUNK = NCB / 16;
  for (int ch = 0; ch < NCHUNK; ch++) {
    __syncthreads();               // prior chunk's gathers done before overwrite
    uint32_t w0 = idxp[(size_t)(ch * 2) * BP + p];
    uint32_t w1 = idxp[(size_t)(ch * 2 + 1) * BP + p];
    {
      const float* g = lut + (((size_t)(ch * 16 + cb_ls)) * 16 + ks) * NOUT + o_base + h * 8;
      float4 va = *(const float4*)g;
      float4 vb = *(const float4*)(g + 4);
      float* sdm = s_lut + cb_ls * 576 + ks * 36 + h * 8;
      *(float4*)sdm = va;
      *(float4*)(sdm + 4) = vb;
    }
    __syncthreads();               // chunk published
#pragma unroll
    for (int cb_l = 0; cb_l < 16; cb_l++) {
      uint32_t w = (cb_l < 8) ? w0 : w1;
      int idx = (int)((w >> (4 * (cb_l & 7))) & 15u);
      const float4 v = *(const float4*)(s_lut + cb_l * 576 + idx * 36 + q * 4);
      a0 += (double)v.x; a1 += (double)v.y; a2 += (double)v.z; a3 += (double)v.w;
    }
  }
  const unsigned b = (unsigned)p / 196u;
  const unsigned pr = (unsigned)p - b * 196u;
  const int o = o_base + q * 4;
  const float4 sc = *(const float4*)(scale + o);
  const float4 bs = *(const float4*)(bias + o);
  double r0 = a0 * (double)sc.x + (double)bs.x;
  double r1 = a1 * (double)sc.y + (double)bs.y;
  double r2 = a2 * (double)sc.z + (double)bs.z;
  double r3 = a3 * (double)sc.w + (double)bs.w;
  if (RES) {
    const float* rp = res + ((size_t)b * NOUT + o) * PP + pr;
    r0 += (double)rp[0 * PP]; r1 += (double)rp[1 * PP];
    r2 += (double)rp[2 * PP]; r3 += (double)rp[3 * PP];
  }
  if (RELU) {
    r0 = fmax(r0, 0.0); r1 = fmax(r1, 0.0);
    r2 = fmax(r2, 0.0); r3 = fmax(r3, 0.0);
  }
  OutT* op = out + ((size_t)b * NOUT + o) * PP + pr;
  op[0 * PP] = (OutT)r0; op[1 * PP] = (OutT)r1;
  op[2 * PP] = (OutT)r2; op[3 * PP] = (OutT)r3;
}

// ---------------------------------------------------------------------------
// accum3: final layer (no downstream argmin). Staging converts f32 LUT ->
// f16 in-register (cvt kernel folded in). Inner loop uses PACKED f16 adds
// (v_pk_add_f16: 4 instr/gather, was 16 scalar cvt+add -> VALU-bound 42us).
// Partials flushed to f32 every 8 codebooks (worst f16 partial err ~0.015).
// Rows 40 halfs (80 B): bank-quad (5*idx+h)%8 bijective -> 2-way = free.
// grid (49, 64), block 256 (4 waves): 128 positions x 16 channels.
// ---------------------------------------------------------------------------
__global__ __launch_bounds__(256) void accum3_f16(
    const float* __restrict__ lut, const uint32_t* __restrict__ idxp,
    const float* __restrict__ scale, const float* __restrict__ bias,
    const float* __restrict__ res, float* __restrict__ out) {
  __shared__ half_t s16[16 * 640];   // 20 KB
  const int t = threadIdx.x;
  const int lane = t & 63;
  const int wave = t >> 6;           // 0..3
  const int h = wave & 1;            // channel half (8 f16 ch)
  const int pg = wave >> 1;          // 0..1
  const int p = blockIdx.x * 128 + pg * 64 + lane;
  const int o_base = blockIdx.y * 16;
  // staging slots s0=t, s1=t+256 of 512: (cb=s>>5, k=(s>>1)&15, hh=s&1)
  const int s0 = t, s1 = t + 256;
  const int cA = s0 >> 5, kA = (s0 >> 1) & 15, hA = s0 & 1;
  const int cB = s1 >> 5, kB = (s1 >> 1) & 15, hB = s1 & 1;
  const size_t cs = (size_t)16 * 16 * 1024;     // 16 cb per chunk (f32 elems)
  constexpr int NCHUNK = 4;
  float acc[8];
#pragma unroll
  for (int i = 0; i < 8; i++) acc[i] = 0.f;
  for (int ch = 0; ch < NCHUNK; ch++) {
    __syncthreads();
    uint32_t w0 = idxp[(size_t)(ch * 2) * BP + p];
    uint32_t w1 = idxp[(size_t)(ch * 2 + 1) * BP + p];
    {
      const float* gA = lut + (size_t)ch * cs + ((size_t)cA * 16 + kA) * 1024 + o_base + hA * 8;
      const float* gB = lut + (size_t)ch * cs + ((size_t)cB * 16 + kB) * 1024 + o_base + hB * 8;
      float4 a0 = *(const float4*)gA;
      float4 a1 = *(const float4*)(gA + 4);
      float4 b0 = *(const float4*)gB;
      float4 b1 = *(const float4*)(gB + 4);
      half8v va, vb;
      va[0] = (half_t)a0.x; va[1] = (half_t)a0.y; va[2] = (half_t)a0.z; va[3] = (half_t)a0.w;
      va[4] = (half_t)a1.x; va[5] = (half_t)a1.y; va[6] = (half_t)a1.z; va[7] = (half_t)a1.w;
      vb[0] = (half_t)b0.x; vb[1] = (half_t)b0.y; vb[2] = (half_t)b0.z; vb[3] = (half_t)b0.w;
      vb[4] = (half_t)b1.x; vb[5] = (half_t)b1.y; vb[6] = (half_t)b1.z; vb[7] = (half_t)b1.w;
      *(half8v*)(s16 + cA * 640 + kA * 40 + hA * 8) = va;
      *(half8v*)(s16 + cB * 640 + kB * 40 + hB * 8) = vb;
    }
    __syncthreads();
#pragma unroll
    for (int half_grp = 0; half_grp < 2; half_grp++) {   // 8 cb per partial
      half2v p0 = 0, p1 = 0, p2 = 0, p3 = 0;
      uint32_t w = half_grp ? w1 : w0;
#pragma unroll
      for (int j = 0; j < 8; j++) {
        int cb_l = half_grp * 8 + j;
        int idx = (int)((w >> (4 * j)) & 15u);
        const half8v v = *(const half8v*)(s16 + cb_l * 640 + idx * 40 + h * 8);
        const half2v* vp = (const half2v*)&v;
        p0 += vp[0]; p1 += vp[1]; p2 += vp[2]; p3 += vp[3];
      }
      acc[0] += (float)p0[0]; acc[1] += (float)p0[1];
      acc[2] += (float)p1[0]; acc[3] += (float)p1[1];
      acc[4] += (float)p2[0]; acc[5] += (float)p2[1];
      acc[6] += (float)p3[0]; acc[7] += (float)p3[1];
    }
  }
  const unsigned b = (unsigned)p / 196u;
  const unsigned pr = (unsigned)p - b * 196u;
  const int o = o_base + h * 8;
  const float* rp = res + ((size_t)b * 1024 + o) * PP + pr;
  float* op = out + ((size_t)b * 1024 + o) * PP + pr;
#pragma unroll
  for (int i = 0; i < 8; i++) {
    float v = acc[i] * scale[o + i] + bias[o + i] + rp[(size_t)i * PP];
    op[(size_t)i * PP] = fmaxf(v, 0.f);
  }
}

// ---------------------------------------------------------------------------

extern "C" void kernel_launch(void* const* d_in, const int* in_sizes, int n_in,
                              void* d_out, int out_size, void* d_ws, size_t ws_size,
                              hipStream_t stream) {
  const float* x   = (const float*)d_in[0];   // [32,1024,14,14]
  const float* c1c = (const float*)d_in[1];
  const float* c1l = (const float*)d_in[2];
  const float* c1s = (const float*)d_in[3];
  const float* c1b = (const float*)d_in[4];
  const float* c2c = (const float*)d_in[5];
  const float* c2l = (const float*)d_in[6];
  const float* c2s = (const float*)d_in[7];
  const float* c2b = (const float*)d_in[8];
  const float* c3c = (const float*)d_in[9];
  const float* c3l = (const float*)d_in[10];  // [64,16,1024]
  const float* c3s = (const float*)d_in[11];
  const float* c3b = (const float*)d_in[12];

  const size_t sz_i1 = (size_t)32 * BP * 4;
  const size_t sz_i2 = (size_t)32 * BP * 4;
  const size_t sz_i3 = (size_t)8 * BP * 4;
  const size_t sz_o64 = (size_t)BP * 256 * 8;   // 12.85 MB

  char* w = (char*)d_ws;
  uint32_t* i1 = (uint32_t*)w; w += sz_i1;
  uint32_t* i2 = (uint32_t*)w; w += sz_i2;
  uint32_t* i3 = (uint32_t*)w; w += sz_i3;
  double *out1, *out2;
  if (ws_size >= (size_t)(w - (char*)d_ws) + 2 * sz_o64) {
    out1 = (double*)w;
    out2 = (double*)(w + sz_o64);
  } else {
    // d_out (25.69 MB f32) == exactly two 12.85 MB f64 arrays; the final
    // accum3 reads only i3/x/lut, then overwrites all of d_out.
    out1 = (double*)d_out;
    out2 = out1 + (size_t)BP * 256;
  }

  const dim3 blkA(256);
  // layer 1: 1x1, 256 codebooks (dsub=4) over 1024 input channels
  assign_1x1<float><<<dim3(25, 32), blkA, 0, stream>>>(x, c1c, i1, 1024);
  accum_f64<256, 256, true, false, double><<<dim3(49, 16), dim3(512), 0, stream>>>(
      c1l, i1, c1s, c1b, nullptr, out1);
  // layer 2: 3x3, 256 codebooks (dsub=9)
  assign_3x3<<<dim3(25, 32), blkA, 0, stream>>>(out1, c2c, i2);
  accum_f64<256, 256, true, false, double><<<dim3(49, 16), dim3(512), 0, stream>>>(
      c2l, i2, c2s, c2b, nullptr, out2);
  // layer 3: 1x1, 64 codebooks over 256 channels; fused residual + relu
  assign_1x1<double><<<dim3(25, 8), blkA, 0, stream>>>(out2, c3c, i3, 256);
  accum3_f16<<<dim3(49, 64), blkA, 0, stream>>>(
      c3l, i3, c3s, c3b, x, (float*)d_out);
}

// Round 9
// 238.091 us; speedup vs baseline: 1.4527x; 1.1188x over previous
//
#include <hip/hip_runtime.h>
#include <stdint.h>

#define PP 196            // 14*14
#define BP 6272           // 32*196

typedef _Float16 half_t;
typedef half_t half8v __attribute__((ext_vector_type(8)));
typedef half_t half2v __attribute__((ext_vector_type(2)));

// ---------------------------------------------------------------------------
// assign kernels (layers 1,2): nearest-centroid 4-bit indices, packed 8/u32.
// f32 SCREEN + f64 FIXUP (R7-proven): screen tracks best/second-best; iff any
// lane's gap < TAU the wave re-runs that codebook with the exact f64 formula.
// idx layout: idxp[cb/8][BP]
// ---------------------------------------------------------------------------

template <typename T>
__global__ __launch_bounds__(256) void assign_1x1(
    const T* __restrict__ in, const float* __restrict__ cents,
    uint32_t* __restrict__ idxp, int nchan) {
  __shared__ float  sf[8][16][4];     // screen rows (16 B, one b128)
  __shared__ double sd[8][16][6];     // [c2, c0..c3, pad]: 48 B rows
  const int chunk = blockIdx.y;
  const int t = threadIdx.x;
  for (int i = t; i < 512; i += 256) {
    float c = cents[(size_t)chunk * 512 + i];
    int cb = i >> 6, r = i & 63;      // r = k*4 + d
    sf[cb][r >> 2][r & 3] = c;
    sd[cb][r >> 2][1 + (r & 3)] = (double)c;
  }
  __syncthreads();
  if (t < 128) {
    int cb = t >> 4, k = t & 15;
    double s = 0.0;
#pragma unroll
    for (int d = 0; d < 4; d++) { double c = sd[cb][k][1 + d]; s += c * c; }
    sd[cb][k][0] = s;
  }
  __syncthreads();
  const int p = blockIdx.x * 256 + t;
  if (p >= BP) return;
  const unsigned b = (unsigned)p / 196u;
  const unsigned pr = (unsigned)p - b * 196u;
  const T* xb = in + ((size_t)b * nchan + chunk * 32) * PP + pr;
  T xr[32];
#pragma unroll
  for (int i = 0; i < 32; i++) xr[i] = xb[(size_t)i * PP];
  float xs2[32];
#pragma unroll
  for (int i = 0; i < 32; i++) xs2[i] = 2.f * (float)xr[i];
  uint32_t word = 0;
#pragma unroll 1
  for (int cb = 0; cb < 8; cb++) {
    float best = 1e30f, sec = 1e30f; int bi = 0;
#pragma unroll
    for (int k = 0; k < 16; k++) {
      const float4 c = *(const float4*)&sf[cb][k][0];
      float dist = c.x * (c.x - xs2[cb * 4 + 0]);
      dist = fmaf(c.y, c.y - xs2[cb * 4 + 1], dist);
      dist = fmaf(c.z, c.z - xs2[cb * 4 + 2], dist);
      dist = fmaf(c.w, c.w - xs2[cb * 4 + 3], dist);
      if (dist < best) { sec = best; best = dist; bi = k; }
      else sec = fminf(sec, dist);
    }
    if (__any(sec - best < 2e-4f)) {
      double xv[4];
#pragma unroll
      for (int d = 0; d < 4; d++) xv[d] = (double)xr[cb * 4 + d];
      double bb = 1e300; int bi64 = 0;
#pragma unroll
      for (int k = 0; k < 16; k++) {
        double dot = 0.0;
#pragma unroll
        for (int d = 0; d < 4; d++) dot = fma(xv[d], sd[cb][k][1 + d], dot);
        double dist = sd[cb][k][0] - 2.0 * dot;
        if (dist < bb) { bb = dist; bi64 = k; }   // strict <: first-min
      }
      bi = bi64;
    }
    word |= (uint32_t)bi << (4 * cb);
  }
  idxp[(size_t)chunk * BP + p] = word;
}

__global__ __launch_bounds__(256) void assign_3x3(
    const double* __restrict__ in, const float* __restrict__ cents,
    uint32_t* __restrict__ idxp) {
  __shared__ float  sf[8][16][12];    // [c2f, c0..c8, pad, pad]: 48 B rows
  __shared__ double sd[8][16][10];    // [c2, c0..c8]: 80 B rows
  const int chunk = blockIdx.y;
  const int c0g = chunk * 8;
  const int t = threadIdx.x;
  for (int i = t; i < 1152; i += 256) {
    int cb = i / 144, r = i - cb * 144;
    int k = r / 9, d = r - k * 9;
    float c = cents[(size_t)(c0g + cb) * 144 + k * 9 + d];
    sf[cb][k][1 + d] = c;
    sd[cb][k][1 + d] = (double)c;
  }
  __syncthreads();
  if (t < 128) {
    int cb = t >> 4, k = t & 15;
    double s = 0.0;
    float s32 = 0.f;
#pragma unroll
    for (int d = 0; d < 9; d++) {
      double c = sd[cb][k][1 + d]; s += c * c;
      float cf = sf[cb][k][1 + d]; s32 += cf * cf;
    }
    sd[cb][k][0] = s;
    sf[cb][k][0] = s32;
  }
  __syncthreads();
  const int p = blockIdx.x * 256 + t;
  if (p >= BP) return;
  const unsigned b = (unsigned)p / 196u;
  const unsigned pr = (unsigned)p - b * 196u;
  const int oh = pr / 14, ow = pr - oh * 14;
  uint32_t word = 0;
#pragma unroll 1
  for (int cb = 0; cb < 8; cb++) {
    const double* base = in + ((size_t)b * 256 + (c0g + cb)) * PP;
    double v64[9]; float v32[9];
#pragma unroll
    for (int r = 0; r < 3; r++) {
#pragma unroll
      for (int cc = 0; cc < 3; cc++) {
        int hh = oh + r - 1, ww = ow + cc - 1;
        bool ok = (hh >= 0) & (hh < 14) & (ww >= 0) & (ww < 14);
        double v = ok ? base[hh * 14 + ww] : 0.0;
        v64[r * 3 + cc] = v;
        v32[r * 3 + cc] = (float)v;
      }
    }
    float best = 1e30f, sec = 1e30f; int bi = 0;
#pragma unroll
    for (int k = 0; k < 16; k++) {
      const float4 cA = *(const float4*)&sf[cb][k][0];  // c2f,c0,c1,c2
      const float4 cB = *(const float4*)&sf[cb][k][4];  // c3..c6
      const float4 cC = *(const float4*)&sf[cb][k][8];  // c7,c8,pad,pad
      float dot = v32[0] * cA.y;
      dot = fmaf(v32[1], cA.z, dot);
      dot = fmaf(v32[2], cA.w, dot);
      dot = fmaf(v32[3], cB.x, dot);
      dot = fmaf(v32[4], cB.y, dot);
      dot = fmaf(v32[5], cB.z, dot);
      dot = fmaf(v32[6], cB.w, dot);
      dot = fmaf(v32[7], cC.x, dot);
      dot = fmaf(v32[8], cC.y, dot);
      float dist = fmaf(-2.f, dot, cA.x);
      if (dist < best) { sec = best; best = dist; bi = k; }
      else sec = fminf(sec, dist);
    }
    if (__any(sec - best < 4e-4f)) {
      double bb = 1e300; int bi64 = 0;
#pragma unroll
      for (int k = 0; k < 16; k++) {
        double dot = 0.0;
#pragma unroll
        for (int d = 0; d < 9; d++) dot = fma(v64[d], sd[cb][k][1 + d], dot);
        double dist = sd[cb][k][0] - 2.0 * dot;
        if (dist < bb) { bb = dist; bi64 = k; }
      }
      bi = bi64;
    }
    word |= (uint32_t)bi << (4 * cb);
  }
  idxp[(size_t)chunk * BP + p] = word;
}

// ---------------------------------------------------------------------------
// accum v2 (f64-grade): out = act(scale*sum_cb lut[cb][idx][o] + bias) per
// (pos, 16 ch). 256-thread blocks (64 pos x 16 ch; q = wave = channel quad),
// grid (98, 16) -> 6.1 blocks/CU (R2's 512-thr/784-block version sat at 3.06
// blocks/CU, 40% occupancy, latency-exposed). Two-barrier staging (proven),
// LDS stride 20 floats: gather bank-quad (5*idx+q)%8 bijective -> 2-way free.
// PAIRWISE accumulation: cb pairs summed in f32 (err ~7e-7 rms << np's own
// f32 noise ~1e-5), then one cvt+f64 add per pair -> halves cvt+f64 work.
// FUSE3 (layer 2): epilogue computes the layer-3 assignment in-register
// (thread's 4 channels == exactly one L3 codebook subvector) and writes one
// byte to i3b[p][cb3] -- eliminates the assign3 kernel AND all out2 traffic.
// ---------------------------------------------------------------------------
template <int NCB, int NOUT, bool RELU, bool FUSE3, typename OutT>
__global__ __launch_bounds__(256) void accum_f64(
    const float* __restrict__ lut, const uint32_t* __restrict__ idxp,
    const float* __restrict__ scale, const float* __restrict__ bias,
    const float* __restrict__ c3cent, uint8_t* __restrict__ i3b,
    OutT* __restrict__ out) {
  __shared__ float s_lut[16 * 16 * 20];   // 20 KB
  __shared__ float  c3f[4][16][4];
  __shared__ float  c3c2f[4][16];
  __shared__ double c3d[4][16][4];
  __shared__ double c3c2d[4][16];
  const int t = threadIdx.x;
  const int lane = t & 63;
  const int q = t >> 6;                 // channel quad 0..3
  const int p = blockIdx.x * 64 + lane; // 98*64 = 6272 = BP exactly
  const int o_base = blockIdx.y * 16;
  if (FUSE3 && t < 64) {
    int cb_l = t >> 4, k = t & 15;
    const float4 cf = *(const float4*)(c3cent + ((size_t)(blockIdx.y * 4 + cb_l)) * 64 + k * 4);
    c3f[cb_l][k][0] = cf.x; c3f[cb_l][k][1] = cf.y;
    c3f[cb_l][k][2] = cf.z; c3f[cb_l][k][3] = cf.w;
    double d0 = (double)cf.x, d1 = (double)cf.y, d2 = (double)cf.z, d3 = (double)cf.w;
    c3d[cb_l][k][0] = d0; c3d[cb_l][k][1] = d1;
    c3d[cb_l][k][2] = d2; c3d[cb_l][k][3] = d3;
    double s = 0.0; s += d0 * d0; s += d1 * d1; s += d2 * d2; s += d3 * d3;
    c3c2d[cb_l][k] = s;
    float s32 = 0.f; s32 += cf.x * cf.x; s32 += cf.y * cf.y;
    s32 += cf.z * cf.z; s32 += cf.w * cf.w;
    c3c2f[cb_l][k] = s32;
  }
  // staging: 1024 slots of 16 B; thread t takes slots t+256j (row srow=slot>>2, scol=slot&3)
  const int srow = t >> 2, scol = t & 3;
  const float* src = lut + (size_t)srow * NOUT + o_base + scol * 4;
  const int d0f = srow * 20 + scol * 4;
  double a0 = 0, a1 = 0, a2 = 0, a3 = 0;
  constexpr int NCHUNK = NCB / 16;
  for (int ch = 0; ch < NCHUNK; ch++) {
    __syncthreads();               // prior chunk's gathers done before overwrite
    uint32_t w0 = idxp[(size_t)(ch * 2) * BP + p];
    uint32_t w1 = idxp[(size_t)(ch * 2 + 1) * BP + p];
    {
      const float* g = src + (size_t)(ch * 256) * NOUT;
#pragma unroll
      for (int j = 0; j < 4; j++) {
        float4 v = *(const float4*)(g + (size_t)(64 * j) * NOUT);
        *(float4*)(s_lut + d0f + j * 1280) = v;
      }
    }
    __syncthreads();               // chunk published
#pragma unroll
    for (int j = 0; j < 8; j++) {  // cb pair (2j, 2j+1)
      uint32_t w = (j < 4) ? w0 : w1;
      int sh = (j & 3) * 8;
      int i0 = (int)((w >> sh) & 15u);
      int i1 = (int)((w >> (sh + 4)) & 15u);
      const float4 va = *(const float4*)(s_lut + (2 * j) * 320 + i0 * 20 + q * 4);
      const float4 vb = *(const float4*)(s_lut + (2 * j + 1) * 320 + i1 * 20 + q * 4);
      float s0 = va.x + vb.x, s1 = va.y + vb.y;
      float s2 = va.z + vb.z, s3 = va.w + vb.w;
      a0 += (double)s0; a1 += (double)s1; a2 += (double)s2; a3 += (double)s3;
    }
  }
  const unsigned b = (unsigned)p / 196u;
  const unsigned pr = (unsigned)p - b * 196u;
  const int o = o_base + q * 4;
  const float4 sc = *(const float4*)(scale + o);
  const float4 bs = *(const float4*)(bias + o);
  double r0 = a0 * (double)sc.x + (double)bs.x;
  double r1 = a1 * (double)sc.y + (double)bs.y;
  double r2 = a2 * (double)sc.z + (double)bs.z;
  double r3 = a3 * (double)sc.w + (double)bs.w;
  if (RELU) {
    r0 = fmax(r0, 0.0); r1 = fmax(r1, 0.0);
    r2 = fmax(r2, 0.0); r3 = fmax(r3, 0.0);
  }
  if (FUSE3) {
    // layer-3 assignment for codebook cb3 = blockIdx.y*4 + q (this thread's 4 ch)
    const int cb_l = q;
    float x0 = (float)r0, x1 = (float)r1, x2 = (float)r2, x3 = (float)r3;
    float best = 1e30f, sec = 1e30f; int bi = 0;
#pragma unroll
    for (int k = 0; k < 16; k++) {
      const float4 c = *(const float4*)&c3f[cb_l][k][0];
      float dot = x0 * c.x;
      dot = fmaf(x1, c.y, dot);
      dot = fmaf(x2, c.z, dot);
      dot = fmaf(x3, c.w, dot);
      float dist = fmaf(-2.f, dot, c3c2f[cb_l][k]);
      if (dist < best) { sec = best; best = dist; bi = k; }
      else sec = fminf(sec, dist);
    }
    if (__any(sec - best < 1e-3f)) {
      double bb = 1e300; int bi64 = 0;
#pragma unroll
      for (int k = 0; k < 16; k++) {
        double dot = 0.0;
        dot = fma(r0, c3d[cb_l][k][0], dot);
        dot = fma(r1, c3d[cb_l][k][1], dot);
        dot = fma(r2, c3d[cb_l][k][2], dot);
        dot = fma(r3, c3d[cb_l][k][3], dot);
        double dist = c3c2d[cb_l][k] - 2.0 * dot;
        if (dist < bb) { bb = dist; bi64 = k; }   // strict <: first-min
      }
      bi = bi64;
    }
    i3b[(size_t)p * 64 + blockIdx.y * 4 + q] = (uint8_t)bi;
  } else {
    OutT* op = out + ((size_t)b * NOUT + o) * PP + pr;
    op[0 * PP] = (OutT)r0; op[1 * PP] = (OutT)r1;
    op[2 * PP] = (OutT)r2; op[3 * PP] = (OutT)r3;
  }
}

// ---------------------------------------------------------------------------
// accum3: final layer (no downstream argmin). f32 LUT -> f16 staged in-register;
// packed v_pk_add_f16 inner loop, partials flushed to f32 every 8 codebooks.
// Index read: one dwordx4 of bytes per chunk from i3b[p][cb]. Rows 40 halfs
// (80 B): bank-quad (5*idx+h)%8 bijective -> 2-way = free.
// grid (49, 64), block 256 (4 waves): 128 positions x 16 channels.
// ---------------------------------------------------------------------------
__global__ __launch_bounds__(256) void accum3_f16(
    const float* __restrict__ lut, const uint8_t* __restrict__ i3b,
    const float* __restrict__ scale, const float* __restrict__ bias,
    const float* __restrict__ res, float* __restrict__ out) {
  __shared__ half_t s16[16 * 640];   // 20 KB
  const int t = threadIdx.x;
  const int lane = t & 63;
  const int wave = t >> 6;           // 0..3
  const int h = wave & 1;            // channel half (8 f16 ch)
  const int pg = wave >> 1;          // 0..1
  const int p = blockIdx.x * 128 + pg * 64 + lane;
  const int o_base = blockIdx.y * 16;
  // staging slots s0=t, s1=t+256 of 512: (cb=s>>5, k=(s>>1)&15, hh=s&1)
  const int s0 = t, s1 = t + 256;
  const int cA = s0 >> 5, kA = (s0 >> 1) & 15, hA = s0 & 1;
  const int cB = s1 >> 5, kB = (s1 >> 1) & 15, hB = s1 & 1;
  const size_t cs = (size_t)16 * 16 * 1024;     // 16 cb per chunk (f32 elems)
  constexpr int NCHUNK = 4;
  float acc[8];
#pragma unroll
  for (int i = 0; i < 8; i++) acc[i] = 0.f;
  for (int ch = 0; ch < NCHUNK; ch++) {
    __syncthreads();
    const uint4 iw = *(const uint4*)(i3b + (size_t)p * 64 + ch * 16);
    {
      const float* gA = lut + (size_t)ch * cs + ((size_t)cA * 16 + kA) * 1024 + o_base + hA * 8;
      const float* gB = lut + (size_t)ch * cs + ((size_t)cB * 16 + kB) * 1024 + o_base + hB * 8;
      float4 a0 = *(const float4*)gA;
      float4 a1 = *(const float4*)(gA + 4);
      float4 b0 = *(const float4*)gB;
      float4 b1 = *(const float4*)(gB + 4);
      half8v va, vb;
      va[0] = (half_t)a0.x; va[1] = (half_t)a0.y; va[2] = (half_t)a0.z; va[3] = (half_t)a0.w;
      va[4] = (half_t)a1.x; va[5] = (half_t)a1.y; va[6] = (half_t)a1.z; va[7] = (half_t)a1.w;
      vb[0] = (half_t)b0.x; vb[1] = (half_t)b0.y; vb[2] = (half_t)b0.z; vb[3] = (half_t)b0.w;
      vb[4] = (half_t)b1.x; vb[5] = (half_t)b1.y; vb[6] = (half_t)b1.z; vb[7] = (half_t)b1.w;
      *(half8v*)(s16 + cA * 640 + kA * 40 + hA * 8) = va;
      *(half8v*)(s16 + cB * 640 + kB * 40 + hB * 8) = vb;
    }
    __syncthreads();
#pragma unroll
    for (int grp = 0; grp < 2; grp++) {   // 8 cb per f32 flush
      uint32_t wa = grp ? iw.z : iw.x;
      uint32_t wb = grp ? iw.w : iw.y;
      half2v p0 = 0, p1 = 0, p2 = 0, p3 = 0;
#pragma unroll
      for (int j = 0; j < 8; j++) {
        uint32_t w = (j < 4) ? wa : wb;
        int idx = (int)((w >> ((j & 3) * 8)) & 15u);
        int cb_l = grp * 8 + j;
        const half8v v = *(const half8v*)(s16 + cb_l * 640 + idx * 40 + h * 8);
        const half2v* vp = (const half2v*)&v;
        p0 += vp[0]; p1 += vp[1]; p2 += vp[2]; p3 += vp[3];
      }
      acc[0] += (float)p0[0]; acc[1] += (float)p0[1];
      acc[2] += (float)p1[0]; acc[3] += (float)p1[1];
      acc[4] += (float)p2[0]; acc[5] += (float)p2[1];
      acc[6] += (float)p3[0]; acc[7] += (float)p3[1];
    }
  }
  const unsigned b = (unsigned)p / 196u;
  const unsigned pr = (unsigned)p - b * 196u;
  const int o = o_base + h * 8;
  const float* rp = res + ((size_t)b * 1024 + o) * PP + pr;
  float* op = out + ((size_t)b * 1024 + o) * PP + pr;
#pragma unroll
  for (int i = 0; i < 8; i++) {
    float v = acc[i] * scale[o + i] + bias[o + i] + rp[(size_t)i * PP];
    op[(size_t)i * PP] = fmaxf(v, 0.f);
  }
}

// ---------------------------------------------------------------------------

extern "C" void kernel_launch(void* const* d_in, const int* in_sizes, int n_in,
                              void* d_out, int out_size, void* d_ws, size_t ws_size,
                              hipStream_t stream) {
  const float* x   = (const float*)d_in[0];   // [32,1024,14,14]
  const float* c1c = (const float*)d_in[1];
  const float* c1l = (const float*)d_in[2];
  const float* c1s = (const float*)d_in[3];
  const float* c1b = (const float*)d_in[4];
  const float* c2c = (const float*)d_in[5];
  const float* c2l = (const float*)d_in[6];
  const float* c2s = (const float*)d_in[7];
  const float* c2b = (const float*)d_in[8];
  const float* c3c = (const float*)d_in[9];
  const float* c3l = (const float*)d_in[10];  // [64,16,1024]
  const float* c3s = (const float*)d_in[11];
  const float* c3b = (const float*)d_in[12];

  const size_t sz_i1  = (size_t)32 * BP * 4;      // 802,816 B
  const size_t sz_i2  = (size_t)32 * BP * 4;
  const size_t sz_i3b = (size_t)BP * 64;          // 401,408 B (byte indices)
  const size_t sz_o64 = (size_t)BP * 256 * 8;     // 12.85 MB

  char* w = (char*)d_ws;
  uint32_t* i1 = (uint32_t*)w; w += sz_i1;
  uint32_t* i2 = (uint32_t*)w; w += sz_i2;
  uint8_t* i3b = (uint8_t*)w;  w += sz_i3b;
  double* out1;
  if (ws_size >= (size_t)(w - (char*)d_ws) + sz_o64) {
    out1 = (double*)w;
  } else {
    // d_out (25.69 MB f32) holds one 12.85 MB f64 array in its first half;
    // accum3 (final) reads only i3b/x/c3l, then overwrites all of d_out.
    out1 = (double*)d_out;
  }

  const dim3 blkA(256), blkC(256);
  // layer 1: 1x1, 256 codebooks (dsub=4) over 1024 input channels
  assign_1x1<float><<<dim3(25, 32), blkA, 0, stream>>>(x, c1c, i1, 1024);
  accum_f64<256, 256, true, false, double><<<dim3(98, 16), blkC, 0, stream>>>(
      c1l, i1, c1s, c1b, nullptr, nullptr, out1);
  // layer 2: 3x3, 256 codebooks (dsub=9); epilogue fuses the layer-3 assign
  assign_3x3<<<dim3(25, 32), blkA, 0, stream>>>(out1, c2c, i2);
  accum_f64<256, 256, true, true, double><<<dim3(98, 16), blkC, 0, stream>>>(
      c2l, i2, c2s, c2b, c3c, i3b, nullptr);
  // layer 3: 64 codebooks over 256 channels; fused residual + relu
  accum3_f16<<<dim3(49, 64), blkC, 0, stream>>>(
      c3l, i3b, c3s, c3b, x, (float*)d_out);
}